// Round 9
// baseline (74.424 us; speedup 1.0000x reference)
//
#include <hip/hip_runtime.h>

// out[b, c, vox] = valid[vox] ? feat[b, cam[vox], c, v[vox], u[vox]] : 0
// feat: (B=4, N=6, C=64, H=64, W=176) f32; out: (B=4, C=64, 240000) f32
//
// P1 transpose feat -> ws (B, N*H*W, C) bf16 channel-last.
// P2 gather: block = (batch-pair, 64-voxel tile); po_s once; software
//    pipeline: batch b+1's random ws loads issued into registers before
//    batch b's store drain; zero-fill of invalid ot columns done once.

constexpr int NB   = 4;
constexpr int NCAM = 6;
constexpr int NC   = 64;
constexpr int NH   = 64;
constexpr int NW   = 176;
constexpr int NVOX = 240000;
constexpr int HW   = NH * NW;        // 11264
constexpr int CHW  = NC * HW;        // 720896
constexpr int NPIX = NCAM * HW;      // 67584 pixels per batch

constexpr int TILES_B  = NVOX / 64;              // 3750 voxel-tiles per batch
constexpr int KPX      = (TILES_B + 3) / 4;      // 938 tiles per XCD in a quad
constexpr int GBLOCKS  = 8 * KPX;                // 7504 (6 exit early)

constexpr size_t WS_NEEDED = (size_t)NB * NPIX * NC * 2;   // 34,603,008

typedef float        f32x4 __attribute__((ext_vector_type(4)));
typedef unsigned int u32x4 __attribute__((ext_vector_type(4)));

__device__ __forceinline__ unsigned short f32_to_bf16_rne(float f) {
    unsigned int u = __float_as_uint(f);
    u += 0x7FFFu + ((u >> 16) & 1u);      // round to nearest even
    return (unsigned short)(u >> 16);
}

// ---------- P1: transpose feat (b,n,C,HW) f32 -> ws (b, n*HW+pix, C) bf16 ----
__global__ __launch_bounds__(256) void transpose_kernel(
    const float* __restrict__ feat, unsigned short* __restrict__ wst)
{
    __shared__ unsigned short lds[64][66];
    const int bid  = blockIdx.x;
    const int tile = bid % (HW / 64);        // 176 tiles
    const int bn   = bid / (HW / 64);        // b*6+n
    const int px0  = tile * 64;
    const int t    = threadIdx.x;

    const float* src = feat + (size_t)bn * CHW + px0;
#pragma unroll
    for (int r = 0; r < 16; ++r) {
        const int c  = r * 4 + (t >> 6);
        const int px = t & 63;
        const float f = __builtin_nontemporal_load(&src[(size_t)c * HW + px]);
        lds[px][c] = f32_to_bf16_rne(f);
    }
    __syncthreads();

    unsigned short* dst = wst + ((size_t)bn * HW + px0) * NC;
#pragma unroll
    for (int j = 0; j < 2; ++j) {
        const int px    = t >> 2;
        const int chunk = (t & 3) + 4 * j;    // 8-channel chunk
        u32x4 o;
#pragma unroll
        for (int p = 0; p < 4; ++p) {
            const unsigned int lo = lds[px][chunk * 8 + 2 * p];
            const unsigned int hi = lds[px][chunk * 8 + 2 * p + 1];
            o[p] = lo | (hi << 16);
        }
        *reinterpret_cast<u32x4*>(dst + (size_t)px * NC + chunk * 8) = o;
    }
}

// ---------- P2: gather, block = (batch-pair, tile), register-pipelined ----
__global__ __launch_bounds__(256) void gather_cl_kernel(
    const unsigned short* __restrict__ wst,
    const int* __restrict__ cam, const int* __restrict__ uu,
    const int* __restrict__ vv,  const int* __restrict__ valid,
    float* __restrict__ out)
{
    __shared__ float ot[64][65];             // [ch][vox]
    __shared__ int   po_s[64];

    // XCD-quad swizzle: xcd = bid%8 heuristic; batch-pair bp = xcd>>2.
    const int xcd  = blockIdx.x & 7;
    const int bp   = xcd >> 2;               // 0: b in {0,1}; 1: b in {2,3}
    const int q    = xcd & 3;
    const int k    = blockIdx.x >> 3;        // [0, 938)
    const int tile = q * KPX + k;
    if (tile >= TILES_B) return;             // uniform per-block exit
    const int vox0 = tile * 64;
    const int t    = threadIdx.x;

    if (t < 64) {
        const int i = vox0 + t;
        po_s[t] = valid[i] ? cam[i] * HW + vv[i] * NW + uu[i] : -1;
    }
    __syncthreads();

    // per-thread fixed (vx, kk) pair for r = 0,1
    const int kk  = t & 7;                   // channel octet
    const int vxA = (t >> 3);                // r=0 voxel  (0..31)
    const int vxB = 32 + vxA;                // r=1 voxel
    const int pixA = po_s[vxA];
    const int pixB = po_s[vxB];

    // zero-fill invalid columns ONCE (valid mask shared across batches)
#pragma unroll
    for (int r = 0; r < 2; ++r) {
        const int vx  = r ? vxB : vxA;
        const int pix = r ? pixB : pixA;
        if (pix < 0) {
#pragma unroll
            for (int e = 0; e < 8; ++e) ot[kk * 8 + e][vx] = 0.0f;
        }
    }

    const int b0 = 2 * bp;
    const unsigned short* wb0 = wst + (size_t)b0 * NPIX * NC;
    const unsigned short* wb1 = wb0 + (size_t)NPIX * NC;

    // prologue: issue batch-0 loads
    u32x4 rA0 = {}, rA1 = {};
    if (pixA >= 0) rA0 = *reinterpret_cast<const u32x4*>(wb0 + (size_t)pixA * NC + kk * 8);
    if (pixB >= 0) rA1 = *reinterpret_cast<const u32x4*>(wb0 + (size_t)pixB * NC + kk * 8);
    // issue batch-1 loads now too: in flight across batch-0 expand + store
    u32x4 rB0 = {}, rB1 = {};
    if (pixA >= 0) rB0 = *reinterpret_cast<const u32x4*>(wb1 + (size_t)pixA * NC + kk * 8);
    if (pixB >= 0) rB1 = *reinterpret_cast<const u32x4*>(wb1 + (size_t)pixB * NC + kk * 8);

#pragma unroll
    for (int bb = 0; bb < 2; ++bb) {
        const u32x4 r0 = bb ? rB0 : rA0;
        const u32x4 r1 = bb ? rB1 : rA1;
        // expand regs -> ot (valid entries only; invalid stay zero)
        if (pixA >= 0) {
#pragma unroll
            for (int p = 0; p < 4; ++p) {
                ot[kk * 8 + 2 * p][vxA]     = __uint_as_float(r0[p] << 16);
                ot[kk * 8 + 2 * p + 1][vxA] = __uint_as_float(r0[p] & 0xFFFF0000u);
            }
        }
        if (pixB >= 0) {
#pragma unroll
            for (int p = 0; p < 4; ++p) {
                ot[kk * 8 + 2 * p][vxB]     = __uint_as_float(r1[p] << 16);
                ot[kk * 8 + 2 * p + 1][vxB] = __uint_as_float(r1[p] & 0xFFFF0000u);
            }
        }
        __syncthreads();

        float* ob = out + (size_t)(b0 + bb) * NC * NVOX + vox0;
#pragma unroll
        for (int i = 0; i < 4; ++i) {
            const int slot = i * 256 + t;
            const int ch   = slot >> 4;      // 4 ch per wave
            const int g    = slot & 15;      // 4-voxel group
            f32x4 val = { ot[ch][4 * g], ot[ch][4 * g + 1],
                          ot[ch][4 * g + 2], ot[ch][4 * g + 3] };
            __builtin_nontemporal_store(val,
                reinterpret_cast<f32x4*>(ob + (size_t)ch * NVOX + 4 * g));
        }
        if (bb == 0) __syncthreads();        // stores read ot before refill
    }
}

// ---------- fallback if ws too small ----------
__global__ __launch_bounds__(256) void gather_direct_kernel(
    const float* __restrict__ feat,
    const int* __restrict__ cam, const int* __restrict__ u,
    const int* __restrict__ v,   const int* __restrict__ valid,
    float* __restrict__ out)
{
    const int NG = NVOX / 4;
    const int t  = blockIdx.x * 256 + threadIdx.x;
    const int g  = t % NG;
    const int bc = t / NG;
    const int c  = bc & (NC - 1);
    const int b  = bc >> 6;
    const int4 c4 = reinterpret_cast<const int4*>(cam)[g];
    const int4 u4 = reinterpret_cast<const int4*>(u)[g];
    const int4 v4 = reinterpret_cast<const int4*>(v)[g];
    const int4 w4 = reinterpret_cast<const int4*>(valid)[g];
    const float* fb = feat + (size_t)b * (NCAM * CHW) + (size_t)c * HW;
    float4 o;
    o.x = w4.x ? fb[c4.x * CHW + v4.x * NW + u4.x] : 0.0f;
    o.y = w4.y ? fb[c4.y * CHW + v4.y * NW + u4.y] : 0.0f;
    o.z = w4.z ? fb[c4.z * CHW + v4.z * NW + u4.z] : 0.0f;
    o.w = w4.w ? fb[c4.w * CHW + v4.w * NW + u4.w] : 0.0f;
    reinterpret_cast<float4*>(out)[t] = o;
}

extern "C" void kernel_launch(void* const* d_in, const int* in_sizes, int n_in,
                              void* d_out, int out_size, void* d_ws, size_t ws_size,
                              hipStream_t stream) {
    const float* feat  = (const float*)d_in[0];
    const int*   cam   = (const int*)d_in[1];
    const int*   u     = (const int*)d_in[2];
    const int*   v     = (const int*)d_in[3];
    const int*   valid = (const int*)d_in[4];
    float* out = (float*)d_out;

    if (ws_size >= WS_NEEDED) {
        unsigned short* wst = (unsigned short*)d_ws;
        transpose_kernel<<<NB * NCAM * (HW / 64), 256, 0, stream>>>(feat, wst);
        gather_cl_kernel<<<GBLOCKS, 256, 0, stream>>>(wst, cam, u, v, valid, out);
    } else {
        const int total = NB * NC * (NVOX / 4);
        gather_direct_kernel<<<total / 256, 256, 0, stream>>>(feat, cam, u, v, valid, out);
    }
}